// Round 21
// baseline (173.685 us; speedup 1.0000x reference)
//
#include <hip/hip_runtime.h>
#include <cstdint>
#include <cmath>

using u16 = unsigned short;
typedef __attribute__((ext_vector_type(4))) short s16x4;
typedef __attribute__((ext_vector_type(8))) short s16x8;
typedef __attribute__((ext_vector_type(8))) __bf16 bf16x8;
typedef __attribute__((ext_vector_type(4))) float f32x4;

static __device__ __forceinline__ float b2f(u16 u) {
    unsigned int x = ((unsigned int)u) << 16;
    float f; __builtin_memcpy(&f, &x, 4); return f;
}
static __device__ __forceinline__ u16 f2b(float f) {
    unsigned int x; __builtin_memcpy(&x, &f, 4);
    x += 0x7FFFu + ((x >> 16) & 1u);           // round-to-nearest-even
    return (u16)(x >> 16);
}
static __device__ __forceinline__ bf16x8 as_bf(s16x8 s) {
    return __builtin_bit_cast(bf16x8, s);
}

// ---- async 16B/lane global->LDS (wave-uniform LDS base, per-lane global src) ----
static __device__ __forceinline__ void stage16(const u16* g, u16* lds_base, int lane) {
#if __has_builtin(__builtin_amdgcn_global_load_lds)
    __builtin_amdgcn_global_load_lds((const __attribute__((address_space(1))) void*)g,
                                     (__attribute__((address_space(3))) void*)lds_base,
                                     16, 0, 0);
#else
    *(s16x8*)(lds_base + (size_t)lane * 8) = *(const s16x8*)g;
#endif
}

// ---- ALL weight transposes+cvt + x conversion in one launch (grid 144x32):
// tx<112: wq/wk/wv -> wqkvT bf16 [5120][2048], wo -> woT [2048][2048]
// tx>=112: x fp32 -> xb bf16 (grid-stride stripe)
__global__ __launch_bounds__(256) void k_wtransAll(const float* __restrict__ wq,
                                                   const float* __restrict__ wk,
                                                   const float* __restrict__ wv,
                                                   const float* __restrict__ wo,
                                                   const float* __restrict__ x,
                                                   u16* __restrict__ wqkvT,
                                                   u16* __restrict__ woT,
                                                   u16* __restrict__ xb) {
    __shared__ u16 tile[64][72];
    int tx = blockIdx.x;
    int tid = threadIdx.x;
    if (tx >= 112) {                     // ---- x fp32 -> bf16 ----
        int bid = (tx - 112) * 32 + blockIdx.y;      // 0..1023
        int i = bid * 256 + tid;
        const int n4 = 2048 * 2048 / 4;
        const int stride = 1024 * 256;
        for (; i < n4; i += stride) {
            f32x4 v = ((const f32x4*)x)[i];
            s16x4 b;
            for (int j = 0; j < 4; ++j) b[j] = (short)f2b(v[j]);
            ((s16x4*)xb)[i] = b;
        }
        return;
    }
    const float* src; int N, nb, base; u16* dst;
    if (tx < 64)      { src = wq; N = 4096; nb = tx * 64;        base = tx * 64;               dst = wqkvT; }
    else if (tx < 72) { src = wk; N = 512;  nb = (tx - 64) * 64; base = 4096 + (tx - 64) * 64; dst = wqkvT; }
    else if (tx < 80) { src = wv; N = 512;  nb = (tx - 72) * 64; base = 4608 + (tx - 72) * 64; dst = wqkvT; }
    else              { src = wo; N = 2048; nb = (tx - 80) * 64; base = (tx - 80) * 64;        dst = woT; }
    int kb = blockIdx.y * 64;
    int kr = tid >> 2, c0 = (tid & 3) * 16;
#pragma unroll
    for (int i = 0; i < 4; ++i) {
        f32x4 v = *(const f32x4*)(src + (size_t)(kb + kr) * N + nb + c0 + i * 4);
        s16x4 b;
        for (int j = 0; j < 4; ++j) b[j] = (short)f2b(v[j]);
        *(s16x4*)&tile[kr][c0 + i * 4] = b;
    }
    __syncthreads();
    int nr = tid >> 2, k0 = (tid & 3) * 16;
    s16x8 v0, v1;
    for (int j = 0; j < 8; ++j) { v0[j] = (short)tile[k0 + j][nr]; v1[j] = (short)tile[k0 + 8 + j][nr]; }
    *(s16x8*)(dst + (size_t)(base + nr) * 2048 + kb + k0) = v0;
    *(s16x8*)(dst + (size_t)(base + nr) * 2048 + kb + k0 + 8) = v1;
}

// ------------- GEMM: BM=128, BN=64, BK=64 — C[M][N] = A[M][K] @ Bt[N][K]^T -------------
// 4 waves (2x2), wave tile 64x32 (acc 4x2), global_load_lds staging with source-baked
// XOR swizzle, XCD bn-band remap + bm snake. High block count for TLP:
// qkv (N=5120): 80x16 = 1280 blocks = 5/CU even; out (N=2048): 32x16 = 512 = 2/CU.
template <bool OUT_F32>
__global__ __launch_bounds__(256) void k_gemm_bn64(const u16* __restrict__ A,
                                                   const u16* __restrict__ Bt,
                                                   void* __restrict__ Cv,
                                                   int M, int N, int K) {
    __shared__ u16 As[128 * 64];
    __shared__ u16 Bs[64 * 64];
    int nx = gridDim.x, ny = gridDim.y;          // nx % 8 == 0
    int flat = blockIdx.y * nx + blockIdx.x;
    int xcd = flat & 7, i = flat >> 3;
    int P = nx >> 3;
    int bnl = i / ny;
    int bmi = i - bnl * ny;
    if (bnl & 1) bmi = ny - 1 - bmi;             // snake: adjacent A-strips
    int bn = (xcd * P + bnl) * 64;
    int bm = bmi * 128;

    int tid = threadIdx.x, wid = tid >> 6, lane = tid & 63;
    int l15 = lane & 15, g = lane >> 4;
    int wr = (wid >> 1) * 64, wc = (wid & 1) * 32;
    f32x4 acc[4][2];
    for (int ii = 0; ii < 4; ++ii) for (int j = 0; j < 2; ++j) acc[ii][j] = f32x4{0.f, 0.f, 0.f, 0.f};

    int srow = lane >> 3;
    int scol = ((lane & 7) * 8) ^ (srow << 3);           // u16 units (XOR involution)
    const u16* pa = A + (size_t)(bm + srow) * K + scol;
    const u16* pb = Bt + (size_t)(bn + srow) * K + scol;

    for (int kb = 0; kb < K; kb += 64) {
        __syncthreads();
#pragma unroll
        for (int it = 0; it < 4; ++it) {
            int c = it * 4 + wid;
            stage16(pa + (size_t)(c * 8) * K + kb, &As[c * 512], lane);
        }
#pragma unroll
        for (int it = 0; it < 2; ++it) {
            int c = it * 4 + wid;
            stage16(pb + (size_t)(c * 8) * K + kb, &Bs[c * 512], lane);
        }
        __syncthreads();
        int swz = (l15 & 7) << 4;
#pragma unroll
        for (int kk = 0; kk < 64; kk += 32) {
            bf16x8 af[4], bfr[2];
            for (int mi = 0; mi < 4; ++mi) {
                const char* rp = (const char*)As + (wr + mi * 16 + l15) * 128;
                af[mi] = as_bf(*(const s16x8*)(rp + ((kk * 2 + g * 16) ^ swz)));
            }
            for (int ni = 0; ni < 2; ++ni) {
                const char* rp = (const char*)Bs + (wc + ni * 16 + l15) * 128;
                bfr[ni] = as_bf(*(const s16x8*)(rp + ((kk * 2 + g * 16) ^ swz)));
            }
            for (int mi = 0; mi < 4; ++mi)
                for (int ni = 0; ni < 2; ++ni)
                    acc[mi][ni] = __builtin_amdgcn_mfma_f32_16x16x32_bf16(af[mi], bfr[ni], acc[mi][ni], 0, 0, 0);
        }
    }
    for (int mi = 0; mi < 4; ++mi)
        for (int ni = 0; ni < 2; ++ni) {
            int row = bm + wr + mi * 16 + g * 4;
            int col = bn + wc + ni * 16 + l15;
            for (int rr = 0; rr < 4; ++rr) {
                if (OUT_F32)
                    ((float*)Cv)[(size_t)(row + rr) * N + col] = acc[mi][ni][rr];
                else
                    ((u16*)Cv)[(size_t)(row + rr) * N + col] = f2b(acc[mi][ni][rr]);
            }
        }
}

// ---- merged RMSNorm+RoPE (blocks 0..2047) + V transpose (blocks 2048..2175) ----
__global__ __launch_bounds__(256) void k_prep_attn(u16* __restrict__ qkv,
                                                   const float* __restrict__ qw,
                                                   const float* __restrict__ kw,
                                                   const int* __restrict__ pos,
                                                   u16* __restrict__ vT) {
    __shared__ u16 tile[64][136];
    int bid = blockIdx.x;
    int tid = threadIdx.x;
    if (bid < 2048) {                    // ---- RMSNorm + RoPE, in place ----
        int t = bid, w = tid >> 6, l = tid & 63;
        float fp = (float)pos[t];
        int j = l & 31;
        float invf = __expf(-(float)j * (9.210340371976184f / 32.f));   // 10000^(-j/32)
        float sv, cv;
        sincosf(fp * invf, &sv, &cv);
        for (int task = w; task < 20; task += 4) {
            u16* p; const float* ww;
            if (task < 16) { p = qkv + (size_t)t * 5120 + task * 256; ww = qw; }
            else           { p = qkv + (size_t)t * 5120 + 4096 + (task - 16) * 128; ww = kw; }
            float v0 = b2f(p[l]), v1 = b2f(p[l + 64]);
            float ss = v0 * v0 + v1 * v1;
            for (int m = 32; m; m >>= 1) ss += __shfl_xor(ss, m);
            float rn = rsqrtf(ss * (1.f / 128.f) + 1e-6f);
            float q0 = v0 * rn * (1.f + ww[l]);
            float q1 = v1 * rn * (1.f + ww[l + 64]);
            float other = __shfl_xor(q0, 32);
            float ro = (l < 32) ? (q0 * cv - other * sv) : (q0 * cv + other * sv);
            p[l] = f2b(ro);
            p[l + 64] = f2b(q1);
        }
    } else {                             // ---- V transpose -> vT[kvh][d][t] ----
        int r = bid - 2048;              // 0..127
        int tb = (r & 31) * 64, kvh = r >> 5;
        int tr = tid >> 2, c0 = (tid & 3) * 32;
        const u16* src = qkv + (size_t)(tb + tr) * 5120 + 4608 + kvh * 128 + c0;
#pragma unroll
        for (int i = 0; i < 4; ++i)
            *(s16x8*)&tile[tr][c0 + i * 8] = *(const s16x8*)(src + i * 8);
        __syncthreads();
        int d = tid >> 1, t0 = (tid & 1) * 32;
        u16* dst = vT + ((size_t)kvh * 128 + d) * 2048 + tb + t0;
#pragma unroll
        for (int i = 0; i < 4; ++i) {
            s16x8 v;
            for (int j = 0; j < 8; ++j) v[j] = (short)tile[t0 + i * 8 + j][d];
            *(s16x8*)(dst + i * 8) = v;
        }
    }
}

// ---------------- causal GQA flash attention, SPLIT-K x4, KVBLK=32, static-max ----------------
__global__ __launch_bounds__(256) void k_attn_split(const u16* __restrict__ qkv,
                                                    const u16* __restrict__ vT,
                                                    u16* __restrict__ po,
                                                    float* __restrict__ pl) {
    __shared__ u16 Kl[32 * 128];       // 8 KB, XOR-swizzled rows of 256B (pre-swz src)
    __shared__ u16 Vt[128][72];        // 18.4 KB [d][key], padded
    __shared__ u16 Pl[4][16][40];      // 5.1 KB per-wave P tile
    int head = blockIdx.y, kvh = head >> 2;
    int p = blockIdx.x >> 2, hf = blockIdx.x & 3;
    int tid = threadIdx.x, wid = tid >> 6, lane = tid & 63;
    int l15 = lane & 15, g = lane >> 4;

    for (int sub = 0; sub < 2; ++sub) {
        int qt = sub ? (31 - p) : p;
        int qb0 = qt * 64;
        int nk = (qt + 1) * 2;               // 32-key tiles
        int ktb = (hf * nk) >> 2;
        int kte = ((hf + 1) * nk) >> 2;

        bf16x8 qf[4];
        {
            const u16* qp = qkv + (size_t)(qb0 + wid * 16 + l15) * 5120 + head * 256 + g * 8;
            for (int c = 0; c < 4; ++c) qf[c] = as_bf(*(const s16x8*)(qp + c * 32));
        }
        f32x4 oacc[8];
        for (int nb = 0; nb < 8; ++nb) oacc[nb] = f32x4{0.f, 0.f, 0.f, 0.f};
        float lsum[4] = {0.f, 0.f, 0.f, 0.f};

        for (int kt = ktb; kt < kte; ++kt) {
            int k0 = kt * 32;
            __syncthreads();
            {   // K: 8 chunks of 1KB (4 key-rows x 256B); wave stages chunks wid*2, wid*2+1
#pragma unroll
                for (int i = 0; i < 2; ++i) {
                    int c = (wid << 1) | i;
                    int srow = (c << 2) + (lane >> 4);
                    int bofs = (((lane & 15) << 4) ^ ((srow & 7) << 4));
                    const u16* gs = (const u16*)((const char*)(qkv + (size_t)(k0 + srow) * 5120
                                                               + 4096 + kvh * 128) + bofs);
                    stage16(gs, &Kl[c * 512], lane);
                }
                // V: each thread 16 keys of one d-row from pre-transposed vT
                int vr = tid >> 1, vc0 = (tid & 1) * 16;
                const u16* vs = vT + ((size_t)kvh * 128 + vr) * 2048 + k0 + vc0;
#pragma unroll
                for (int c = 0; c < 2; ++c)
                    *(s16x8*)&Vt[vr][vc0 + 8 * c] = *(const s16x8*)(vs + 8 * c);
            }
            __syncthreads();

            f32x4 sc2[2];
            sc2[0] = f32x4{0.f, 0.f, 0.f, 0.f}; sc2[1] = f32x4{0.f, 0.f, 0.f, 0.f};
            for (int h2 = 0; h2 < 2; ++h2) {
                int krow = h2 * 16 + l15;
                const char* kb_ = (const char*)Kl + krow * 256;
                int sw = (krow & 7) << 4;
                for (int c = 0; c < 4; ++c) {
                    bf16x8 kf = as_bf(*(const s16x8*)(kb_ + ((c * 64 + g * 16) ^ sw)));
                    sc2[h2] = __builtin_amdgcn_mfma_f32_16x16x32_bf16(qf[c], kf, sc2[h2], 0, 0, 0);
                }
            }
            // static-max softmax: |scores| <= sqrt(128)*scale ~ 11.32, exp <= 8.2e4
            const float scale = 0.08838834764831845f;   // 1/sqrt(128)
            for (int r = 0; r < 4; ++r) {
                int tq = qb0 + wid * 16 + g * 4 + r;
                float pv0 = (k0 + l15 > tq) ? 0.f : __expf(sc2[0][r] * scale);
                float pv1 = (k0 + 16 + l15 > tq) ? 0.f : __expf(sc2[1][r] * scale);
                Pl[wid][g * 4 + r][l15] = f2b(pv0);
                Pl[wid][g * 4 + r][16 + l15] = f2b(pv1);
                lsum[r] += pv0 + pv1;
            }
            bf16x8 pa = as_bf(*(const s16x8*)&Pl[wid][l15][g * 8]);
            for (int nb = 0; nb < 8; ++nb) {
                bf16x8 vb = as_bf(*(const s16x8*)&Vt[nb * 16 + l15][g * 8]);
                oacc[nb] = __builtin_amdgcn_mfma_f32_16x16x32_bf16(pa, vb, oacc[nb], 0, 0, 0);
            }
        }
        // epilogue: deferred l reduce + partial writes ([hf][t][h*128+d] layout)
        u16* pob = po + (size_t)hf * (2048 * 2048);
        float* plb = pl + hf * (16 * 2048) + head * 2048;
        for (int r = 0; r < 4; ++r) {
            float s = lsum[r];
            s += __shfl_xor(s, 1, 16); s += __shfl_xor(s, 2, 16);
            s += __shfl_xor(s, 4, 16); s += __shfl_xor(s, 8, 16);
            int row = qb0 + wid * 16 + g * 4 + r;
            if (l15 == 0) plb[row] = s;
            for (int nb = 0; nb < 8; ++nb)
                pob[(size_t)row * 2048 + head * 128 + nb * 16 + l15] = f2b(oacc[nb][r]);
        }
    }
}

// ---- combine 4 partials + sigmoid gate, IN PLACE into po slice 0 (= out-GEMM A) ----
__global__ __launch_bounds__(256) void k_combine(u16* __restrict__ po,
                                                 const float* __restrict__ pl,
                                                 const u16* __restrict__ qkv) {
    int t = blockIdx.x;
    int tid = threadIdx.x;
    int h = tid >> 4, d0 = (tid & 15) * 8;
    const size_t S = (size_t)2048 * 2048;
    const size_t base = (size_t)t * 2048 + h * 128 + d0;
    s16x8 a = *(const s16x8*)(po + base);
    s16x8 b = *(const s16x8*)(po + S + base);
    s16x8 c = *(const s16x8*)(po + 2 * S + base);
    s16x8 d = *(const s16x8*)(po + 3 * S + base);
    int li = h * 2048 + t;
    float l = pl[li] + pl[16 * 2048 + li] + pl[32 * 2048 + li] + pl[48 * 2048 + li];
    float inv = 1.f / l;
    s16x8 o;
    for (int j = 0; j < 8; ++j) {
        float y = (b2f((u16)a[j]) + b2f((u16)b[j]) + b2f((u16)c[j]) + b2f((u16)d[j])) * inv;
        float gt = b2f(qkv[(size_t)t * 5120 + h * 256 + 128 + d0 + j]);
        o[j] = (short)f2b(y / (1.f + __expf(-gt)));
    }
    *(s16x8*)(po + base) = o;            // in-place: slice 0 becomes gated y
}

// ---------------- launch ----------------
extern "C" void kernel_launch(void* const* d_in, const int* in_sizes, int n_in,
                              void* d_out, int out_size, void* d_ws, size_t ws_size,
                              hipStream_t stream) {
    const float* x   = (const float*)d_in[0];
    const int*   pos = (const int*)d_in[1];
    const float* wq  = (const float*)d_in[2];
    const float* wk  = (const float*)d_in[3];
    const float* wv  = (const float*)d_in[4];
    const float* wo  = (const float*)d_in[5];
    const float* qnw = (const float*)d_in[6];
    const float* knw = (const float*)d_in[7];
    float* out = (float*)d_out;
    char* ws = (char*)d_ws;

    // workspace (peak 65.6 MB; ws_size >= 69.2 MB proven in round 1):
    u16*   qkv   = (u16*)(ws + 0);          // 2048x5120 bf16 (21.0 MB)       [phase2+]
    u16*   woT   = (u16*)(ws + 20971520);   // 2048x2048 bf16 (8.4 MB)        [all]
    u16*   wqkvT = (u16*)(ws + 29360128);   // 5120x2048 bf16 (21.0 MB)       [phase1-2]
    u16*   xb    = (u16*)(ws + 50331648);   // 2048x2048 bf16 (8.4 MB)        [phase1-2]
    u16*   vTb   = (u16*)(ws + 29360128);   // 4x128x2048 bf16 (2.1 MB)       [phase3+, over dead wqkvT]
    u16*   pob   = (u16*)(ws + 31457280);   // 4x2048x2048 bf16 (33.6 MB)     [phase4+, over dead wqkvT/xb]
    float* plb   = (float*)(ws + 65011712); // 4x16x2048 fp32 (524 KB)        [phase4+]

    k_wtransAll<<<dim3(144, 32), 256, 0, stream>>>(wq, wk, wv, wo, x, wqkvT, woT, xb);

    k_gemm_bn64<false><<<dim3(80, 16), 256, 0, stream>>>(xb, wqkvT, qkv, 2048, 5120, 2048);

    k_prep_attn<<<2176, 256, 0, stream>>>(qkv, qnw, knw, pos, vTb);

    k_attn_split<<<dim3(64, 16), 256, 0, stream>>>(qkv, vTb, pob, plb);
    k_combine<<<2048, 256, 0, stream>>>(pob, plb, qkv);

    k_gemm_bn64<true><<<dim3(32, 16), 256, 0, stream>>>(pob, woT, out, 2048, 2048, 2048);
}

// Round 22
// 167.911 us; speedup vs baseline: 1.0344x; 1.0344x over previous
//
#include <hip/hip_runtime.h>
#include <cstdint>
#include <cmath>

using u16 = unsigned short;
typedef __attribute__((ext_vector_type(4))) short s16x4;
typedef __attribute__((ext_vector_type(8))) short s16x8;
typedef __attribute__((ext_vector_type(8))) __bf16 bf16x8;
typedef __attribute__((ext_vector_type(4))) float f32x4;

static __device__ __forceinline__ float b2f(u16 u) {
    unsigned int x = ((unsigned int)u) << 16;
    float f; __builtin_memcpy(&f, &x, 4); return f;
}
static __device__ __forceinline__ u16 f2b(float f) {
    unsigned int x; __builtin_memcpy(&x, &f, 4);
    x += 0x7FFFu + ((x >> 16) & 1u);           // round-to-nearest-even
    return (u16)(x >> 16);
}
static __device__ __forceinline__ bf16x8 as_bf(s16x8 s) {
    return __builtin_bit_cast(bf16x8, s);
}

// ---- async 16B/lane global->LDS (wave-uniform LDS base, per-lane global src) ----
static __device__ __forceinline__ void stage16(const u16* g, u16* lds_base, int lane) {
#if __has_builtin(__builtin_amdgcn_global_load_lds)
    __builtin_amdgcn_global_load_lds((const __attribute__((address_space(1))) void*)g,
                                     (__attribute__((address_space(3))) void*)lds_base,
                                     16, 0, 0);
#else
    *(s16x8*)(lds_base + (size_t)lane * 8) = *(const s16x8*)g;
#endif
}

// ---- ALL weight transposes+cvt + x conversion in one launch (grid 144x32):
// tx<112: wq/wk/wv -> wqkvT bf16 [5120][2048], wo -> woT [2048][2048]
// tx>=112: x fp32 -> xb bf16 (grid-stride stripe)
__global__ __launch_bounds__(256) void k_wtransAll(const float* __restrict__ wq,
                                                   const float* __restrict__ wk,
                                                   const float* __restrict__ wv,
                                                   const float* __restrict__ wo,
                                                   const float* __restrict__ x,
                                                   u16* __restrict__ wqkvT,
                                                   u16* __restrict__ woT,
                                                   u16* __restrict__ xb) {
    __shared__ u16 tile[64][72];
    int tx = blockIdx.x;
    int tid = threadIdx.x;
    if (tx >= 112) {                     // ---- x fp32 -> bf16 ----
        int bid = (tx - 112) * 32 + blockIdx.y;      // 0..1023
        int i = bid * 256 + tid;
        const int n4 = 2048 * 2048 / 4;
        const int stride = 1024 * 256;
        for (; i < n4; i += stride) {
            f32x4 v = ((const f32x4*)x)[i];
            s16x4 b;
            for (int j = 0; j < 4; ++j) b[j] = (short)f2b(v[j]);
            ((s16x4*)xb)[i] = b;
        }
        return;
    }
    const float* src; int N, nb, base; u16* dst;
    if (tx < 64)      { src = wq; N = 4096; nb = tx * 64;        base = tx * 64;               dst = wqkvT; }
    else if (tx < 72) { src = wk; N = 512;  nb = (tx - 64) * 64; base = 4096 + (tx - 64) * 64; dst = wqkvT; }
    else if (tx < 80) { src = wv; N = 512;  nb = (tx - 72) * 64; base = 4608 + (tx - 72) * 64; dst = wqkvT; }
    else              { src = wo; N = 2048; nb = (tx - 80) * 64; base = (tx - 80) * 64;        dst = woT; }
    int kb = blockIdx.y * 64;
    int kr = tid >> 2, c0 = (tid & 3) * 16;
#pragma unroll
    for (int i = 0; i < 4; ++i) {
        f32x4 v = *(const f32x4*)(src + (size_t)(kb + kr) * N + nb + c0 + i * 4);
        s16x4 b;
        for (int j = 0; j < 4; ++j) b[j] = (short)f2b(v[j]);
        *(s16x4*)&tile[kr][c0 + i * 4] = b;
    }
    __syncthreads();
    int nr = tid >> 2, k0 = (tid & 3) * 16;
    s16x8 v0, v1;
    for (int j = 0; j < 8; ++j) { v0[j] = (short)tile[k0 + j][nr]; v1[j] = (short)tile[k0 + 8 + j][nr]; }
    *(s16x8*)(dst + (size_t)(base + nr) * 2048 + kb + k0) = v0;
    *(s16x8*)(dst + (size_t)(base + nr) * 2048 + kb + k0 + 8) = v1;
}

// ------------- GEMM: C[M][N] = A[M][K] @ Bt[N][K]^T  (bf16 in, fp32 acc) -------------
// 128x128 tile, BK=64, 4 waves (2x2), global_load_lds staging with source-baked
// XOR swizzle. XCD bn-band remap + bm snake. PURE compute kernel.
template <bool OUT_F32>
__global__ __launch_bounds__(256) void k_gemm_bt(const u16* __restrict__ A,
                                                 const u16* __restrict__ Bt,
                                                 void* __restrict__ Cv,
                                                 int M, int N, int K) {
    __shared__ u16 As[128 * 64];
    __shared__ u16 Bs[128 * 64];
    int nx = gridDim.x, ny = gridDim.y;          // nx % 8 == 0
    int flat = blockIdx.y * nx + blockIdx.x;
    int xcd = flat & 7, i = flat >> 3;
    int P = nx >> 3;
    int bnl = i / ny;
    int bmi = i - bnl * ny;
    if (bnl & 1) bmi = ny - 1 - bmi;             // snake: adjacent A-strips
    int bn = (xcd * P + bnl) * 128;
    int bm = bmi * 128;

    int tid = threadIdx.x, wid = tid >> 6, lane = tid & 63;
    int l15 = lane & 15, g = lane >> 4;
    int wr = (wid >> 1) * 64, wc = (wid & 1) * 64;
    f32x4 acc[4][4];
    for (int ii = 0; ii < 4; ++ii) for (int j = 0; j < 4; ++j) acc[ii][j] = f32x4{0.f, 0.f, 0.f, 0.f};

    int srow = lane >> 3;
    int scol = ((lane & 7) * 8) ^ (srow << 3);           // u16 units (XOR involution)
    const u16* pa = A + (size_t)(bm + srow) * K + scol;
    const u16* pb = Bt + (size_t)(bn + srow) * K + scol;

    for (int kb = 0; kb < K; kb += 64) {
        __syncthreads();
#pragma unroll
        for (int it = 0; it < 4; ++it) {
            int c = it * 4 + wid;
            stage16(pa + (size_t)(c * 8) * K + kb, &As[c * 512], lane);
            stage16(pb + (size_t)(c * 8) * K + kb, &Bs[c * 512], lane);
        }
        __syncthreads();
        int swz = (l15 & 7) << 4;
#pragma unroll
        for (int kk = 0; kk < 64; kk += 32) {
            bf16x8 af[4], bfr[4];
            for (int mi = 0; mi < 4; ++mi) {
                const char* rp = (const char*)As + (wr + mi * 16 + l15) * 128;
                af[mi] = as_bf(*(const s16x8*)(rp + ((kk * 2 + g * 16) ^ swz)));
            }
            for (int ni = 0; ni < 4; ++ni) {
                const char* rp = (const char*)Bs + (wc + ni * 16 + l15) * 128;
                bfr[ni] = as_bf(*(const s16x8*)(rp + ((kk * 2 + g * 16) ^ swz)));
            }
            for (int mi = 0; mi < 4; ++mi)
                for (int ni = 0; ni < 4; ++ni)
                    acc[mi][ni] = __builtin_amdgcn_mfma_f32_16x16x32_bf16(af[mi], bfr[ni], acc[mi][ni], 0, 0, 0);
        }
    }
    for (int mi = 0; mi < 4; ++mi)
        for (int ni = 0; ni < 4; ++ni) {
            int row = bm + wr + mi * 16 + g * 4;
            int col = bn + wc + ni * 16 + l15;
            for (int rr = 0; rr < 4; ++rr) {
                if (OUT_F32)
                    ((float*)Cv)[(size_t)(row + rr) * N + col] = acc[mi][ni][rr];
                else
                    ((u16*)Cv)[(size_t)(row + rr) * N + col] = f2b(acc[mi][ni][rr]);
            }
        }
}

// ------------- GEMM variant: BM=128, BN=64 (fp32 out) — for the 2048x2048 out-proj -------------
// Grid 32x16 = 512 blocks = 2/CU (the 128x128 version gives only 1/CU at this shape).
// Wave tile 64x32 (acc 4x2). Same staging/swizzle/remap pattern.
__global__ __launch_bounds__(256) void k_gemm_bt64(const u16* __restrict__ A,
                                                   const u16* __restrict__ Bt,
                                                   float* __restrict__ C,
                                                   int M, int N, int K) {
    __shared__ u16 As[128 * 64];
    __shared__ u16 Bs[64 * 64];
    int nx = gridDim.x, ny = gridDim.y;          // nx % 8 == 0
    int flat = blockIdx.y * nx + blockIdx.x;
    int xcd = flat & 7, i = flat >> 3;
    int P = nx >> 3;
    int bnl = i / ny;
    int bmi = i - bnl * ny;
    if (bnl & 1) bmi = ny - 1 - bmi;
    int bn = (xcd * P + bnl) * 64;
    int bm = bmi * 128;

    int tid = threadIdx.x, wid = tid >> 6, lane = tid & 63;
    int l15 = lane & 15, g = lane >> 4;
    int wr = (wid >> 1) * 64, wc = (wid & 1) * 32;
    f32x4 acc[4][2];
    for (int ii = 0; ii < 4; ++ii) for (int j = 0; j < 2; ++j) acc[ii][j] = f32x4{0.f, 0.f, 0.f, 0.f};

    int srow = lane >> 3;
    int scol = ((lane & 7) * 8) ^ (srow << 3);           // u16 units (XOR involution)
    const u16* pa = A + (size_t)(bm + srow) * K + scol;
    const u16* pb = Bt + (size_t)(bn + srow) * K + scol;

    for (int kb = 0; kb < K; kb += 64) {
        __syncthreads();
#pragma unroll
        for (int it = 0; it < 4; ++it) {
            int c = it * 4 + wid;
            stage16(pa + (size_t)(c * 8) * K + kb, &As[c * 512], lane);
        }
#pragma unroll
        for (int it = 0; it < 2; ++it) {
            int c = it * 4 + wid;
            stage16(pb + (size_t)(c * 8) * K + kb, &Bs[c * 512], lane);
        }
        __syncthreads();
        int swz = (l15 & 7) << 4;
#pragma unroll
        for (int kk = 0; kk < 64; kk += 32) {
            bf16x8 af[4], bfr[2];
            for (int mi = 0; mi < 4; ++mi) {
                const char* rp = (const char*)As + (wr + mi * 16 + l15) * 128;
                af[mi] = as_bf(*(const s16x8*)(rp + ((kk * 2 + g * 16) ^ swz)));
            }
            for (int ni = 0; ni < 2; ++ni) {
                const char* rp = (const char*)Bs + (wc + ni * 16 + l15) * 128;
                bfr[ni] = as_bf(*(const s16x8*)(rp + ((kk * 2 + g * 16) ^ swz)));
            }
            for (int mi = 0; mi < 4; ++mi)
                for (int ni = 0; ni < 2; ++ni)
                    acc[mi][ni] = __builtin_amdgcn_mfma_f32_16x16x32_bf16(af[mi], bfr[ni], acc[mi][ni], 0, 0, 0);
        }
    }
    for (int mi = 0; mi < 4; ++mi)
        for (int ni = 0; ni < 2; ++ni) {
            int row = bm + wr + mi * 16 + g * 4;
            int col = bn + wc + ni * 16 + l15;
            for (int rr = 0; rr < 4; ++rr)
                C[(size_t)(row + rr) * N + col] = acc[mi][ni][rr];
        }
}

// ---- merged RMSNorm+RoPE (blocks 0..2047) + V transpose (blocks 2048..2175) ----
__global__ __launch_bounds__(256) void k_prep_attn(u16* __restrict__ qkv,
                                                   const float* __restrict__ qw,
                                                   const float* __restrict__ kw,
                                                   const int* __restrict__ pos,
                                                   u16* __restrict__ vT) {
    __shared__ u16 tile[64][136];
    int bid = blockIdx.x;
    int tid = threadIdx.x;
    if (bid < 2048) {                    // ---- RMSNorm + RoPE, in place ----
        int t = bid, w = tid >> 6, l = tid & 63;
        float fp = (float)pos[t];
        int j = l & 31;
        float invf = __expf(-(float)j * (9.210340371976184f / 32.f));   // 10000^(-j/32)
        float sv, cv;
        sincosf(fp * invf, &sv, &cv);
        for (int task = w; task < 20; task += 4) {
            u16* p; const float* ww;
            if (task < 16) { p = qkv + (size_t)t * 5120 + task * 256; ww = qw; }
            else           { p = qkv + (size_t)t * 5120 + 4096 + (task - 16) * 128; ww = kw; }
            float v0 = b2f(p[l]), v1 = b2f(p[l + 64]);
            float ss = v0 * v0 + v1 * v1;
            for (int m = 32; m; m >>= 1) ss += __shfl_xor(ss, m);
            float rn = rsqrtf(ss * (1.f / 128.f) + 1e-6f);
            float q0 = v0 * rn * (1.f + ww[l]);
            float q1 = v1 * rn * (1.f + ww[l + 64]);
            float other = __shfl_xor(q0, 32);
            float ro = (l < 32) ? (q0 * cv - other * sv) : (q0 * cv + other * sv);
            p[l] = f2b(ro);
            p[l + 64] = f2b(q1);
        }
    } else {                             // ---- V transpose -> vT[kvh][d][t] ----
        int r = bid - 2048;              // 0..127
        int tb = (r & 31) * 64, kvh = r >> 5;
        int tr = tid >> 2, c0 = (tid & 3) * 32;
        const u16* src = qkv + (size_t)(tb + tr) * 5120 + 4608 + kvh * 128 + c0;
#pragma unroll
        for (int i = 0; i < 4; ++i)
            *(s16x8*)&tile[tr][c0 + i * 8] = *(const s16x8*)(src + i * 8);
        __syncthreads();
        int d = tid >> 1, t0 = (tid & 1) * 32;
        u16* dst = vT + ((size_t)kvh * 128 + d) * 2048 + tb + t0;
#pragma unroll
        for (int i = 0; i < 4; ++i) {
            s16x8 v;
            for (int j = 0; j < 8; ++j) v[j] = (short)tile[t0 + i * 8 + j][d];
            *(s16x8*)(dst + i * 8) = v;
        }
    }
}

// ---------------- causal GQA flash attention, SPLIT-K x4, KVBLK=32, static-max ----------------
__global__ __launch_bounds__(256) void k_attn_split(const u16* __restrict__ qkv,
                                                    const u16* __restrict__ vT,
                                                    u16* __restrict__ po,
                                                    float* __restrict__ pl) {
    __shared__ u16 Kl[32 * 128];       // 8 KB, XOR-swizzled rows of 256B (pre-swz src)
    __shared__ u16 Vt[128][72];        // 18.4 KB [d][key], padded
    __shared__ u16 Pl[4][16][40];      // 5.1 KB per-wave P tile
    int head = blockIdx.y, kvh = head >> 2;
    int p = blockIdx.x >> 2, hf = blockIdx.x & 3;
    int tid = threadIdx.x, wid = tid >> 6, lane = tid & 63;
    int l15 = lane & 15, g = lane >> 4;

    for (int sub = 0; sub < 2; ++sub) {
        int qt = sub ? (31 - p) : p;
        int qb0 = qt * 64;
        int nk = (qt + 1) * 2;               // 32-key tiles
        int ktb = (hf * nk) >> 2;
        int kte = ((hf + 1) * nk) >> 2;

        bf16x8 qf[4];
        {
            const u16* qp = qkv + (size_t)(qb0 + wid * 16 + l15) * 5120 + head * 256 + g * 8;
            for (int c = 0; c < 4; ++c) qf[c] = as_bf(*(const s16x8*)(qp + c * 32));
        }
        f32x4 oacc[8];
        for (int nb = 0; nb < 8; ++nb) oacc[nb] = f32x4{0.f, 0.f, 0.f, 0.f};
        float lsum[4] = {0.f, 0.f, 0.f, 0.f};

        for (int kt = ktb; kt < kte; ++kt) {
            int k0 = kt * 32;
            __syncthreads();
            {   // K: 8 chunks of 1KB (4 key-rows x 256B); wave stages chunks wid*2, wid*2+1
#pragma unroll
                for (int i = 0; i < 2; ++i) {
                    int c = (wid << 1) | i;
                    int srow = (c << 2) + (lane >> 4);
                    int bofs = (((lane & 15) << 4) ^ ((srow & 7) << 4));
                    const u16* gs = (const u16*)((const char*)(qkv + (size_t)(k0 + srow) * 5120
                                                               + 4096 + kvh * 128) + bofs);
                    stage16(gs, &Kl[c * 512], lane);
                }
                // V: each thread 16 keys of one d-row from pre-transposed vT
                int vr = tid >> 1, vc0 = (tid & 1) * 16;
                const u16* vs = vT + ((size_t)kvh * 128 + vr) * 2048 + k0 + vc0;
#pragma unroll
                for (int c = 0; c < 2; ++c)
                    *(s16x8*)&Vt[vr][vc0 + 8 * c] = *(const s16x8*)(vs + 8 * c);
            }
            __syncthreads();

            f32x4 sc2[2];
            sc2[0] = f32x4{0.f, 0.f, 0.f, 0.f}; sc2[1] = f32x4{0.f, 0.f, 0.f, 0.f};
            for (int h2 = 0; h2 < 2; ++h2) {
                int krow = h2 * 16 + l15;
                const char* kb_ = (const char*)Kl + krow * 256;
                int sw = (krow & 7) << 4;
                for (int c = 0; c < 4; ++c) {
                    bf16x8 kf = as_bf(*(const s16x8*)(kb_ + ((c * 64 + g * 16) ^ sw)));
                    sc2[h2] = __builtin_amdgcn_mfma_f32_16x16x32_bf16(qf[c], kf, sc2[h2], 0, 0, 0);
                }
            }
            // static-max softmax: |scores| <= sqrt(128)*scale ~ 11.32, exp <= 8.2e4
            const float scale = 0.08838834764831845f;   // 1/sqrt(128)
            for (int r = 0; r < 4; ++r) {
                int tq = qb0 + wid * 16 + g * 4 + r;
                float pv0 = (k0 + l15 > tq) ? 0.f : __expf(sc2[0][r] * scale);
                float pv1 = (k0 + 16 + l15 > tq) ? 0.f : __expf(sc2[1][r] * scale);
                Pl[wid][g * 4 + r][l15] = f2b(pv0);
                Pl[wid][g * 4 + r][16 + l15] = f2b(pv1);
                lsum[r] += pv0 + pv1;
            }
            bf16x8 pa = as_bf(*(const s16x8*)&Pl[wid][l15][g * 8]);
            for (int nb = 0; nb < 8; ++nb) {
                bf16x8 vb = as_bf(*(const s16x8*)&Vt[nb * 16 + l15][g * 8]);
                oacc[nb] = __builtin_amdgcn_mfma_f32_16x16x32_bf16(pa, vb, oacc[nb], 0, 0, 0);
            }
        }
        // epilogue: deferred l reduce + partial writes ([hf][t][h*128+d] layout)
        u16* pob = po + (size_t)hf * (2048 * 2048);
        float* plb = pl + hf * (16 * 2048) + head * 2048;
        for (int r = 0; r < 4; ++r) {
            float s = lsum[r];
            s += __shfl_xor(s, 1, 16); s += __shfl_xor(s, 2, 16);
            s += __shfl_xor(s, 4, 16); s += __shfl_xor(s, 8, 16);
            int row = qb0 + wid * 16 + g * 4 + r;
            if (l15 == 0) plb[row] = s;
            for (int nb = 0; nb < 8; ++nb)
                pob[(size_t)row * 2048 + head * 128 + nb * 16 + l15] = f2b(oacc[nb][r]);
        }
    }
}

// ---- combine 4 partials + sigmoid gate, IN PLACE into po slice 0 (= out-GEMM A) ----
__global__ __launch_bounds__(256) void k_combine(u16* __restrict__ po,
                                                 const float* __restrict__ pl,
                                                 const u16* __restrict__ qkv) {
    int t = blockIdx.x;
    int tid = threadIdx.x;
    int h = tid >> 4, d0 = (tid & 15) * 8;
    const size_t S = (size_t)2048 * 2048;
    const size_t base = (size_t)t * 2048 + h * 128 + d0;
    s16x8 a = *(const s16x8*)(po + base);
    s16x8 b = *(const s16x8*)(po + S + base);
    s16x8 c = *(const s16x8*)(po + 2 * S + base);
    s16x8 d = *(const s16x8*)(po + 3 * S + base);
    int li = h * 2048 + t;
    float l = pl[li] + pl[16 * 2048 + li] + pl[32 * 2048 + li] + pl[48 * 2048 + li];
    float inv = 1.f / l;
    s16x8 o;
    for (int j = 0; j < 8; ++j) {
        float y = (b2f((u16)a[j]) + b2f((u16)b[j]) + b2f((u16)c[j]) + b2f((u16)d[j])) * inv;
        float gt = b2f(qkv[(size_t)t * 5120 + h * 256 + 128 + d0 + j]);
        o[j] = (short)f2b(y / (1.f + __expf(-gt)));
    }
    *(s16x8*)(po + base) = o;            // in-place: slice 0 becomes gated y
}

// ---------------- launch ----------------
extern "C" void kernel_launch(void* const* d_in, const int* in_sizes, int n_in,
                              void* d_out, int out_size, void* d_ws, size_t ws_size,
                              hipStream_t stream) {
    const float* x   = (const float*)d_in[0];
    const int*   pos = (const int*)d_in[1];
    const float* wq  = (const float*)d_in[2];
    const float* wk  = (const float*)d_in[3];
    const float* wv  = (const float*)d_in[4];
    const float* wo  = (const float*)d_in[5];
    const float* qnw = (const float*)d_in[6];
    const float* knw = (const float*)d_in[7];
    float* out = (float*)d_out;
    char* ws = (char*)d_ws;

    // workspace (peak 65.6 MB; ws_size >= 69.2 MB proven in round 1):
    u16*   qkv   = (u16*)(ws + 0);          // 2048x5120 bf16 (21.0 MB)       [phase2+]
    u16*   woT   = (u16*)(ws + 20971520);   // 2048x2048 bf16 (8.4 MB)        [all]
    u16*   wqkvT = (u16*)(ws + 29360128);   // 5120x2048 bf16 (21.0 MB)       [phase1-2]
    u16*   xb    = (u16*)(ws + 50331648);   // 2048x2048 bf16 (8.4 MB)        [phase1-2]
    u16*   vTb   = (u16*)(ws + 29360128);   // 4x128x2048 bf16 (2.1 MB)       [phase3+, over dead wqkvT]
    u16*   pob   = (u16*)(ws + 31457280);   // 4x2048x2048 bf16 (33.6 MB)     [phase4+, over dead wqkvT/xb]
    float* plb   = (float*)(ws + 65011712); // 4x16x2048 fp32 (524 KB)        [phase4+]

    k_wtransAll<<<dim3(144, 32), 256, 0, stream>>>(wq, wk, wv, wo, x, wqkvT, woT, xb);

    k_gemm_bt<false><<<dim3(40, 16), 256, 0, stream>>>(xb, wqkvT, qkv, 2048, 5120, 2048);

    k_prep_attn<<<2176, 256, 0, stream>>>(qkv, qnw, knw, pos, vTb);

    k_attn_split<<<dim3(64, 16), 256, 0, stream>>>(qkv, vTb, pob, plb);
    k_combine<<<2048, 256, 0, stream>>>(pob, plb, qkv);

    k_gemm_bt64<<<dim3(32, 16), 256, 0, stream>>>(pob, woT, out, 2048, 2048, 2048);
}